// Round 5
// baseline (4312.932 us; speedup 1.0000x reference)
//
#include <hip/hip_runtime.h>

#define CPG 8
#define NGRP 32
#define NB 16
#define HW 3136
#define HU 784       // float4 units per channel image
#define N2 36
#define N3 120

typedef float vfloat4 __attribute__((ext_vector_type(4)));
typedef float vfloat2 __attribute__((ext_vector_type(2)));

__host__ __device__ constexpr int idx2(int i, int j) {
    return i * CPG - i * (i - 1) / 2 + (j - i);
}
__host__ __device__ constexpr int idx3(int a, int b, int c) {
    int base = 0;
    for (int t = 0; t < a; ++t) { int m = CPG - t; base += m * (m + 1) / 2; }
    for (int t = a; t < b; ++t) base += CPG - t;
    return base + (c - b);
}

__device__ inline vfloat2 splat2(float s) { return (vfloat2){s, s}; }

// feature (T0,T1) = 4 pixels as two fp32 pairs; weights via two broadcast
// ds_read_b128. __builtin_elementwise_fma on v2f32 -> llvm.fma.v2f32 ->
// V_PK_FMA_F32 (packed dual fp32): 16 pk-fma replace 32 v_fmac_f32.
#define ACCUM(F, T0, T1) do {                                                  \
    const vfloat4 wa = *reinterpret_cast<const vfloat4*>(&wt[(F)][0]);         \
    const vfloat4 wb = *reinterpret_cast<const vfloat4*>(&wt[(F)][4]);         \
    acc[0][0] = __builtin_elementwise_fma(splat2(wa.x), (T0), acc[0][0]);      \
    acc[0][1] = __builtin_elementwise_fma(splat2(wa.x), (T1), acc[0][1]);      \
    acc[1][0] = __builtin_elementwise_fma(splat2(wa.y), (T0), acc[1][0]);      \
    acc[1][1] = __builtin_elementwise_fma(splat2(wa.y), (T1), acc[1][1]);      \
    acc[2][0] = __builtin_elementwise_fma(splat2(wa.z), (T0), acc[2][0]);      \
    acc[2][1] = __builtin_elementwise_fma(splat2(wa.z), (T1), acc[2][1]);      \
    acc[3][0] = __builtin_elementwise_fma(splat2(wa.w), (T0), acc[3][0]);      \
    acc[3][1] = __builtin_elementwise_fma(splat2(wa.w), (T1), acc[3][1]);      \
    acc[4][0] = __builtin_elementwise_fma(splat2(wb.x), (T0), acc[4][0]);      \
    acc[4][1] = __builtin_elementwise_fma(splat2(wb.x), (T1), acc[4][1]);      \
    acc[5][0] = __builtin_elementwise_fma(splat2(wb.y), (T0), acc[5][0]);      \
    acc[5][1] = __builtin_elementwise_fma(splat2(wb.y), (T1), acc[5][1]);      \
    acc[6][0] = __builtin_elementwise_fma(splat2(wb.z), (T0), acc[6][0]);      \
    acc[6][1] = __builtin_elementwise_fma(splat2(wb.z), (T1), acc[6][1]);      \
    acc[7][0] = __builtin_elementwise_fma(splat2(wb.w), (T0), acc[7][0]);      \
    acc[7][1] = __builtin_elementwise_fma(splat2(wb.w), (T1), acc[7][1]);      \
} while (0)

// scheduler fence: prevents mass ds_read hoisting -> bounded register pressure
#define FENCE() __builtin_amdgcn_sched_barrier(0)

__global__ __launch_bounds__(256, 4) void hoaf_kernel(
    const float* __restrict__ x,
    const float* __restrict__ w1, const float* __restrict__ b1,
    const float* __restrict__ w2, const float* __restrict__ b2,
    const float* __restrict__ w3, const float* __restrict__ b3,
    float* __restrict__ out)
{
    // wt[f][o]: f 0-7 deg1, 8-43 deg2, 44-163 deg3, 164 = summed bias
    __shared__ __align__(16) float wt[165][8];

    const int tid   = threadIdx.x;
    const int g     = blockIdx.x;   // block-uniform group
    const int b     = blockIdx.y;
    const int chunk = blockIdx.z;   // 0..3; chunk 3 is a 16-unit runt

    for (int idx = tid; idx < 165 * 8; idx += 256) {
        const int f = idx >> 3, o = idx & 7;
        const int ch = g * CPG + o;
        float v;
        if (f < 8)        v = w1[ch * CPG + f];
        else if (f < 44)  v = w2[ch * N2 + (f - 8)];
        else if (f < 164) v = w3[ch * N3 + (f - 44)];
        else              v = b1[ch] + b2[ch] + b3[ch];
        wt[f][o] = v;
    }
    __syncthreads();

    const int q = tid + chunk * 256;   // one float4 body per thread
    if (q >= HU) return;

    const size_t base = ((size_t)(b * NGRP + g) * CPG) * HW;
    const vfloat4* x4 = (const vfloat4*)(x + base);
    vfloat4*       o4 = (vfloat4*)(out + base);

    vfloat2 xv[CPG][2];
#pragma unroll
    for (int c = 0; c < CPG; ++c) {
        const vfloat4 v = x4[(size_t)c * HU + q];
        xv[c][0] = (vfloat2){v.x, v.y};
        xv[c][1] = (vfloat2){v.z, v.w};
    }

    vfloat2 acc[CPG][2];
#pragma unroll
    for (int o = 0; o < CPG; ++o) {
        acc[o][0] = splat2(wt[164][o]);
        acc[o][1] = acc[o][0];
    }

    // degree 1, fenced every 2 features
#pragma unroll
    for (int k = 0; k < CPG; k += 2) {
        ACCUM(k, xv[k][0], xv[k][1]);
        ACCUM(k + 1, xv[k + 1][0], xv[k + 1][1]);
        FENCE();
    }

    // degree 2 & 3: pair product (i<=j) feeds triples (a<=i<=j);
    // one fence per (i,j) group keeps <= ~10 weight b128s in flight
#pragma unroll
    for (int i = 0; i < CPG; ++i) {
#pragma unroll
        for (int j = i; j < CPG; ++j) {
            const vfloat2 p0 = xv[i][0] * xv[j][0];
            const vfloat2 p1 = xv[i][1] * xv[j][1];
            ACCUM(8 + idx2(i, j), p0, p1);
#pragma unroll
            for (int a = 0; a <= i; ++a) {
                const vfloat2 t0 = xv[a][0] * p0;
                const vfloat2 t1 = xv[a][1] * p1;
                ACCUM(44 + idx3(a, i, j), t0, t1);
            }
            FENCE();
        }
    }

#pragma unroll
    for (int o = 0; o < CPG; ++o) {
        const vfloat4 r = (vfloat4){acc[o][0].x, acc[o][0].y,
                                    acc[o][1].x, acc[o][1].y};
        o4[(size_t)o * HU + q] = r;
    }
}

extern "C" void kernel_launch(void* const* d_in, const int* in_sizes, int n_in,
                              void* d_out, int out_size, void* d_ws, size_t ws_size,
                              hipStream_t stream) {
    const float* x  = (const float*)d_in[0];
    const float* w1 = (const float*)d_in[1];
    const float* b1 = (const float*)d_in[2];
    const float* w2 = (const float*)d_in[3];
    const float* b2 = (const float*)d_in[4];
    const float* w3 = (const float*)d_in[5];
    const float* b3 = (const float*)d_in[6];
    float* out = (float*)d_out;

    dim3 grid(NGRP, NB, 4);   // (group, batch, pixel-chunk) — chunk slowest
    dim3 block(256);
    hoaf_kernel<<<grid, block, 0, stream>>>(x, w1, b1, w2, b2, w3, b3, out);
}

// Round 6
// 183.062 us; speedup vs baseline: 23.5600x; 23.5600x over previous
//
#include <hip/hip_runtime.h>

#define CPG 8
#define NGRP 32
#define NB 16
#define HW 3136
#define HU 784       // float4 units per channel image
#define N2 36
#define N3 120

typedef float vfloat4 __attribute__((ext_vector_type(4)));

__host__ __device__ constexpr int idx2(int i, int j) {
    return i * CPG - i * (i - 1) / 2 + (j - i);
}
__host__ __device__ constexpr int idx3(int a, int b, int c) {
    int base = 0;
    for (int t = 0; t < a; ++t) { int m = CPG - t; base += m * (m + 1) / 2; }
    for (int t = a; t < b; ++t) base += CPG - t;
    return base + (c - b);
}

__device__ inline vfloat4 splat4(float s) { return (vfloat4){s, s, s, s}; }

// feature T (vfloat4 = 4 pixels) x wt[F][0..8): two broadcast ds_read_b128 + 32 fmac
#define ACCUM(F, T) do {                                                       \
    const vfloat4 wa = *reinterpret_cast<const vfloat4*>(&wt[(F)][0]);         \
    const vfloat4 wb = *reinterpret_cast<const vfloat4*>(&wt[(F)][4]);         \
    acc[0] += wa.x * (T); acc[1] += wa.y * (T);                                \
    acc[2] += wa.z * (T); acc[3] += wa.w * (T);                                \
    acc[4] += wb.x * (T); acc[5] += wb.y * (T);                                \
    acc[6] += wb.z * (T); acc[7] += wb.w * (T);                                \
} while (0)

// scheduler fence: prevents mass ds_read hoisting -> bounded register pressure
#define FENCE() __builtin_amdgcn_sched_barrier(0)

// 8 blocks/CU: grid (32*16*4 = 2048) == 256 CU x 8 -> whole grid co-resident,
// zero dispatch tail, 8 waves/SIMD to overlap the LDS and VALU pipes.
// VGPR measured 44 -> fits the 64-reg cap without spill.
__global__ __launch_bounds__(256, 8) void hoaf_kernel(
    const float* __restrict__ x,
    const float* __restrict__ w1, const float* __restrict__ b1,
    const float* __restrict__ w2, const float* __restrict__ b2,
    const float* __restrict__ w3, const float* __restrict__ b3,
    float* __restrict__ out)
{
    // wt[f][o]: f 0-7 deg1, 8-43 deg2, 44-163 deg3, 164 = summed bias
    __shared__ __align__(16) float wt[165][8];

    const int tid   = threadIdx.x;
    const int g     = blockIdx.x;   // block-uniform group
    const int b     = blockIdx.y;
    const int chunk = blockIdx.z;   // 0..3; chunk 3 is a 16-unit runt

    for (int idx = tid; idx < 165 * 8; idx += 256) {
        const int f = idx >> 3, o = idx & 7;
        const int ch = g * CPG + o;
        float v;
        if (f < 8)        v = w1[ch * CPG + f];
        else if (f < 44)  v = w2[ch * N2 + (f - 8)];
        else if (f < 164) v = w3[ch * N3 + (f - 44)];
        else              v = b1[ch] + b2[ch] + b3[ch];
        wt[f][o] = v;
    }
    __syncthreads();

    const int q = tid + chunk * 256;   // one float4 body per thread
    if (q >= HU) return;

    const vfloat4 b_lo = *reinterpret_cast<const vfloat4*>(&wt[164][0]);
    const vfloat4 b_hi = *reinterpret_cast<const vfloat4*>(&wt[164][4]);

    const size_t base = ((size_t)(b * NGRP + g) * CPG) * HW;
    const vfloat4* x4 = (const vfloat4*)(x + base);
    vfloat4*       o4 = (vfloat4*)(out + base);

    vfloat4 xv[CPG];
#pragma unroll
    for (int c = 0; c < CPG; ++c) xv[c] = x4[(size_t)c * HU + q];

    vfloat4 acc[CPG];
    acc[0] = splat4(b_lo.x); acc[1] = splat4(b_lo.y);
    acc[2] = splat4(b_lo.z); acc[3] = splat4(b_lo.w);
    acc[4] = splat4(b_hi.x); acc[5] = splat4(b_hi.y);
    acc[6] = splat4(b_hi.z); acc[7] = splat4(b_hi.w);

    // degree 1, fenced every 2 features
#pragma unroll
    for (int k = 0; k < CPG; k += 2) {
        ACCUM(k, xv[k]);
        ACCUM(k + 1, xv[k + 1]);
        FENCE();
    }

    // degree 2 & 3: pair product (i<=j) feeds triples (a<=i<=j);
    // one fence per (i,j) group keeps <= ~10 weight b128s in flight
#pragma unroll
    for (int i = 0; i < CPG; ++i) {
#pragma unroll
        for (int j = i; j < CPG; ++j) {
            const vfloat4 p = xv[i] * xv[j];
            ACCUM(8 + idx2(i, j), p);
#pragma unroll
            for (int a = 0; a <= i; ++a) {
                const vfloat4 t = xv[a] * p;
                ACCUM(44 + idx3(a, i, j), t);
            }
            FENCE();
        }
    }

#pragma unroll
    for (int o = 0; o < CPG; ++o) o4[(size_t)o * HU + q] = acc[o];
}

extern "C" void kernel_launch(void* const* d_in, const int* in_sizes, int n_in,
                              void* d_out, int out_size, void* d_ws, size_t ws_size,
                              hipStream_t stream) {
    const float* x  = (const float*)d_in[0];
    const float* w1 = (const float*)d_in[1];
    const float* b1 = (const float*)d_in[2];
    const float* w2 = (const float*)d_in[3];
    const float* b2 = (const float*)d_in[4];
    const float* w3 = (const float*)d_in[5];
    const float* b3 = (const float*)d_in[6];
    float* out = (float*)d_out;

    dim3 grid(NGRP, NB, 4);   // (group, batch, pixel-chunk) — chunk slowest
    dim3 block(256);
    hoaf_kernel<<<grid, block, 0, stream>>>(x, w1, b1, w2, b2, w3, b3, out);
}

// Round 7
// 158.627 us; speedup vs baseline: 27.1891x; 1.1540x over previous
//
#include <hip/hip_runtime.h>

#define CPG 8
#define NGRP 32
#define NB 16
#define HW 3136
#define HU 784       // float4 units per channel image
#define N2 36
#define N3 120

typedef float vfloat4 __attribute__((ext_vector_type(4)));

__host__ __device__ constexpr int idx2(int i, int j) {
    return i * CPG - i * (i - 1) / 2 + (j - i);
}
__host__ __device__ constexpr int idx3(int a, int b, int c) {
    int base = 0;
    for (int t = 0; t < a; ++t) { int m = CPG - t; base += m * (m + 1) / 2; }
    for (int t = a; t < b; ++t) base += CPG - t;
    return base + (c - b);
}

__device__ inline vfloat4 splat4(float s) { return (vfloat4){s, s, s, s}; }

// feature T (vfloat4 = 4 pixels) x wt[F][0..8): two broadcast ds_read_b128 + 32 fmac
#define ACCUM(F, T) do {                                                       \
    const vfloat4 wa = *reinterpret_cast<const vfloat4*>(&wt[(F)][0]);         \
    const vfloat4 wb = *reinterpret_cast<const vfloat4*>(&wt[(F)][4]);         \
    acc[0] += wa.x * (T); acc[1] += wa.y * (T);                                \
    acc[2] += wa.z * (T); acc[3] += wa.w * (T);                                \
    acc[4] += wb.x * (T); acc[5] += wb.y * (T);                                \
    acc[6] += wb.z * (T); acc[7] += wb.w * (T);                                \
} while (0)

// scheduler fence: prevents mass ds_read hoisting -> bounded register pressure
#define FENCE() __builtin_amdgcn_sched_barrier(0)

// Occupancy ladder (measured): arg 3 -> 27%, 4 -> 34%/68.5us, 8 -> 68% but
// VGPR cap 64 < ~70-reg live set -> spills (FETCH +142MB, 120us). arg 6 sets
// the cap at 512/6 ~= 85 regs — above the live set, below the spill cliff —
// for 6 blocks/CU of latency hiding.
__global__ __launch_bounds__(256, 6) void hoaf_kernel(
    const float* __restrict__ x,
    const float* __restrict__ w1, const float* __restrict__ b1,
    const float* __restrict__ w2, const float* __restrict__ b2,
    const float* __restrict__ w3, const float* __restrict__ b3,
    float* __restrict__ out)
{
    // wt[f][o]: f 0-7 deg1, 8-43 deg2, 44-163 deg3, 164 = summed bias
    __shared__ __align__(16) float wt[165][8];

    const int tid   = threadIdx.x;
    const int g     = blockIdx.x;   // block-uniform group
    const int b     = blockIdx.y;
    const int chunk = blockIdx.z;   // 0..3; chunk 3 is a 16-unit runt

    for (int idx = tid; idx < 165 * 8; idx += 256) {
        const int f = idx >> 3, o = idx & 7;
        const int ch = g * CPG + o;
        float v;
        if (f < 8)        v = w1[ch * CPG + f];
        else if (f < 44)  v = w2[ch * N2 + (f - 8)];
        else if (f < 164) v = w3[ch * N3 + (f - 44)];
        else              v = b1[ch] + b2[ch] + b3[ch];
        wt[f][o] = v;
    }
    __syncthreads();

    const int q = tid + chunk * 256;   // one float4 body per thread
    if (q >= HU) return;

    const vfloat4 b_lo = *reinterpret_cast<const vfloat4*>(&wt[164][0]);
    const vfloat4 b_hi = *reinterpret_cast<const vfloat4*>(&wt[164][4]);

    const size_t base = ((size_t)(b * NGRP + g) * CPG) * HW;
    const vfloat4* x4 = (const vfloat4*)(x + base);
    vfloat4*       o4 = (vfloat4*)(out + base);

    vfloat4 xv[CPG];
#pragma unroll
    for (int c = 0; c < CPG; ++c) xv[c] = x4[(size_t)c * HU + q];

    vfloat4 acc[CPG];
    acc[0] = splat4(b_lo.x); acc[1] = splat4(b_lo.y);
    acc[2] = splat4(b_lo.z); acc[3] = splat4(b_lo.w);
    acc[4] = splat4(b_hi.x); acc[5] = splat4(b_hi.y);
    acc[6] = splat4(b_hi.z); acc[7] = splat4(b_hi.w);

    // degree 1, fenced every 2 features
#pragma unroll
    for (int k = 0; k < CPG; k += 2) {
        ACCUM(k, xv[k]);
        ACCUM(k + 1, xv[k + 1]);
        FENCE();
    }

    // degree 2 & 3: pair product (i<=j) feeds triples (a<=i<=j);
    // one fence per (i,j) group keeps <= ~10 weight b128s in flight
#pragma unroll
    for (int i = 0; i < CPG; ++i) {
#pragma unroll
        for (int j = i; j < CPG; ++j) {
            const vfloat4 p = xv[i] * xv[j];
            ACCUM(8 + idx2(i, j), p);
#pragma unroll
            for (int a = 0; a <= i; ++a) {
                const vfloat4 t = xv[a] * p;
                ACCUM(44 + idx3(a, i, j), t);
            }
            FENCE();
        }
    }

#pragma unroll
    for (int o = 0; o < CPG; ++o) o4[(size_t)o * HU + q] = acc[o];
}

extern "C" void kernel_launch(void* const* d_in, const int* in_sizes, int n_in,
                              void* d_out, int out_size, void* d_ws, size_t ws_size,
                              hipStream_t stream) {
    const float* x  = (const float*)d_in[0];
    const float* w1 = (const float*)d_in[1];
    const float* b1 = (const float*)d_in[2];
    const float* w2 = (const float*)d_in[3];
    const float* b2 = (const float*)d_in[4];
    const float* w3 = (const float*)d_in[5];
    const float* b3 = (const float*)d_in[6];
    float* out = (float*)d_out;

    dim3 grid(NGRP, NB, 4);   // (group, batch, pixel-chunk) — chunk slowest
    dim3 block(256);
    hoaf_kernel<<<grid, block, 0, stream>>>(x, w1, b1, w2, b2, w3, b3, out);
}

// Round 8
// 156.648 us; speedup vs baseline: 27.5327x; 1.0126x over previous
//
#include <hip/hip_runtime.h>
#include <array>

#define CPG 8
#define NGRP 32
#define NB 16
#define HW 3136
#define HU 784       // float4 units per channel image
#define N2 36
#define N3 120

typedef float vfloat4 __attribute__((ext_vector_type(4)));

__host__ __device__ constexpr int idx2(int i, int j) {
    return i * CPG - i * (i - 1) / 2 + (j - i);
}
__host__ __device__ constexpr int idx3(int a, int b, int c) {
    int base = 0;
    for (int t = 0; t < a; ++t) { int m = CPG - t; base += m * (m + 1) / 2; }
    for (int t = a; t < b; ++t) base += CPG - t;
    return base + (c - b);
}

__device__ inline vfloat4 splat4(float s) { return (vfloat4){s, s, s, s}; }

// Flat feature schedule. Each entry: wt row + how to build the feature value.
// pi>=0 && pj>=0 : p = xv[pi]*xv[pj], t = p          (new degree-2 pair)
// pi>=0 && pj<0  : t = xv[pi]                        (degree-1)
// pi<0           : t = xv[a]*p                       (degree-3, reuses p)
struct Feat { short row; signed char pi, pj, a; };

constexpr std::array<Feat, 164> make_feats() {
    std::array<Feat, 164> t{};
    int n = 0;
    for (int k = 0; k < CPG; ++k)
        t[n++] = Feat{(short)k, (signed char)k, (signed char)-1, (signed char)-1};
    for (int i = 0; i < CPG; ++i)
        for (int j = i; j < CPG; ++j) {
            t[n++] = Feat{(short)(8 + idx2(i, j)), (signed char)i, (signed char)j,
                          (signed char)-1};
            for (int a = 0; a <= i; ++a)
                t[n++] = Feat{(short)(44 + idx3(a, i, j)), (signed char)-1,
                              (signed char)-1, (signed char)a};
        }
    return t;
}

// per-iteration fence: pins the 3-stage rolling pipeline in place — reads for
// feature n+2 issue exactly one region ahead of the fmacs that consume them
// two regions later (~136 VALU cycles of cover vs ~120-cycle LDS latency).
#define FENCE() __builtin_amdgcn_sched_barrier(0)

__global__ __launch_bounds__(256, 4) void hoaf_kernel(
    const float* __restrict__ x,
    const float* __restrict__ w1, const float* __restrict__ b1,
    const float* __restrict__ w2, const float* __restrict__ b2,
    const float* __restrict__ w3, const float* __restrict__ b3,
    float* __restrict__ out)
{
    // wt[f][o]: f 0-7 deg1, 8-43 deg2, 44-163 deg3, 164 = summed bias
    __shared__ __align__(16) float wt[165][8];

    const int tid   = threadIdx.x;
    const int g     = blockIdx.x;   // block-uniform group
    const int b     = blockIdx.y;
    const int chunk = blockIdx.z;   // 0..3; chunk 3 is a 16-unit runt

    for (int idx = tid; idx < 165 * 8; idx += 256) {
        const int f = idx >> 3, o = idx & 7;
        const int ch = g * CPG + o;
        float v;
        if (f < 8)        v = w1[ch * CPG + f];
        else if (f < 44)  v = w2[ch * N2 + (f - 8)];
        else if (f < 164) v = w3[ch * N3 + (f - 44)];
        else              v = b1[ch] + b2[ch] + b3[ch];
        wt[f][o] = v;
    }
    __syncthreads();

    const int q = tid + chunk * 256;   // one float4 body per thread
    if (q >= HU) return;

    const vfloat4 b_lo = *reinterpret_cast<const vfloat4*>(&wt[164][0]);
    const vfloat4 b_hi = *reinterpret_cast<const vfloat4*>(&wt[164][4]);

    const size_t base = ((size_t)(b * NGRP + g) * CPG) * HW;
    const vfloat4* x4 = (const vfloat4*)(x + base);
    vfloat4*       o4 = (vfloat4*)(out + base);

    vfloat4 xv[CPG];
#pragma unroll
    for (int c = 0; c < CPG; ++c) xv[c] = x4[(size_t)c * HU + q];

    vfloat4 acc[CPG];
    acc[0] = splat4(b_lo.x); acc[1] = splat4(b_lo.y);
    acc[2] = splat4(b_lo.z); acc[3] = splat4(b_lo.w);
    acc[4] = splat4(b_hi.x); acc[5] = splat4(b_hi.y);
    acc[6] = splat4(b_hi.z); acc[7] = splat4(b_hi.w);

    constexpr auto FT = make_feats();

#define LDW(row, off) (*reinterpret_cast<const vfloat4*>(&wt[(row)][(off)]))

    // 3-stage rolling weight pipeline: stage0 = consume, stage2 = just issued
    vfloat4 wa0 = LDW(FT[0].row, 0), wb0 = LDW(FT[0].row, 4);
    vfloat4 wa1 = LDW(FT[1].row, 0), wb1 = LDW(FT[1].row, 4);
    vfloat4 p = splat4(0.0f);   // running pair product (set at first deg-2)

#pragma unroll
    for (int n = 0; n < 164; ++n) {
        const int pfrow = (n + 2 < 164) ? FT[n + 2].row : 164;  // 164 = bias row (benign)
        const vfloat4 wa2 = LDW(pfrow, 0);
        const vfloat4 wb2 = LDW(pfrow, 4);

        vfloat4 t;
        if (FT[n].pi >= 0 && FT[n].pj >= 0) {        // new degree-2 pair
            p = xv[FT[n].pi] * xv[FT[n].pj];
            t = p;
        } else if (FT[n].pi >= 0) {                  // degree-1
            t = xv[FT[n].pi];
        } else {                                     // degree-3, reuse p
            t = xv[FT[n].a] * p;
        }

        acc[0] += wa0.x * t; acc[1] += wa0.y * t;
        acc[2] += wa0.z * t; acc[3] += wa0.w * t;
        acc[4] += wb0.x * t; acc[5] += wb0.y * t;
        acc[6] += wb0.z * t; acc[7] += wb0.w * t;

        wa0 = wa1; wb0 = wb1;
        wa1 = wa2; wb1 = wb2;
        FENCE();
    }
#undef LDW

#pragma unroll
    for (int o = 0; o < CPG; ++o) o4[(size_t)o * HU + q] = acc[o];
}

extern "C" void kernel_launch(void* const* d_in, const int* in_sizes, int n_in,
                              void* d_out, int out_size, void* d_ws, size_t ws_size,
                              hipStream_t stream) {
    const float* x  = (const float*)d_in[0];
    const float* w1 = (const float*)d_in[1];
    const float* b1 = (const float*)d_in[2];
    const float* w2 = (const float*)d_in[3];
    const float* b2 = (const float*)d_in[4];
    const float* w3 = (const float*)d_in[5];
    const float* b3 = (const float*)d_in[6];
    float* out = (float*)d_out;

    dim3 grid(NGRP, NB, 4);   // (group, batch, pixel-chunk) — chunk slowest
    dim3 block(256);
    hoaf_kernel<<<grid, block, 0, stream>>>(x, w1, b1, w2, b2, w3, b3, out);
}